// Round 3
// baseline (2398.478 us; speedup 1.0000x reference)
//
#include <hip/hip_runtime.h>
#include <hip/hip_bf16.h>

#define N_NODES 50000
#define F_IN 256
#define HID 128
#define NH 8
#define DH 16
#define NE 800000
#define NM 3
#define NOUT 8
#define NEG 0.2f

// ---------------- K1: h = features @ W_fc + b_fc ----------------
__global__ __launch_bounds__(128) void k_fc(const float* __restrict__ feat,
                                            const float* __restrict__ Wfc,
                                            const float* __restrict__ bfc,
                                            float* __restrict__ h) {
    __shared__ float row[F_IN];
    int n = blockIdx.x;
    int j = threadIdx.x;
    row[j]       = feat[n * F_IN + j];
    row[j + 128] = feat[n * F_IN + j + 128];
    __syncthreads();
    float acc = bfc[j];
    #pragma unroll 8
    for (int k = 0; k < F_IN; k++) acc += row[k] * Wfc[k * HID + j];
    h[n * HID + j] = acc;
}

// ---------------- K2: fs = h@Wsrc, fd = h@Wdst, el, er ----------------
__global__ __launch_bounds__(128) void k_proj(const float* __restrict__ h,
                                              const float* __restrict__ Wsrc,
                                              const float* __restrict__ Wdst,
                                              const float* __restrict__ al,
                                              const float* __restrict__ ar,
                                              float* __restrict__ fs,
                                              float* __restrict__ el,
                                              float* __restrict__ er) {
    __shared__ float row[HID];
    __shared__ float ps[HID];
    __shared__ float pr[HID];
    int n = blockIdx.x;
    int j = threadIdx.x;
    row[j] = h[n * HID + j];
    __syncthreads();
    float a = 0.f, b = 0.f;
    #pragma unroll 8
    for (int k = 0; k < HID; k++) {
        float hv = row[k];
        a += hv * Wsrc[k * HID + j];
        b += hv * Wdst[k * HID + j];
    }
    fs[n * HID + j] = a;
    ps[j] = a * al[j];
    pr[j] = b * ar[j];
    __syncthreads();
    if (j < NH) {
        float sl = 0.f, sr = 0.f;
        #pragma unroll
        for (int d = 0; d < DH; d++) { sl += ps[j * DH + d]; sr += pr[j * DH + d]; }
        el[n * NH + j] = sl;
        er[n * NH + j] = sr;
    }
}

// ---------------- K3: ssum[dst,h] += exp(lrelu(el[src,h]+er[dst,h])) ----------------
__global__ __launch_bounds__(256) void k_esum(const int* __restrict__ src,
                                              const int* __restrict__ dst,
                                              const float* __restrict__ el,
                                              const float* __restrict__ er,
                                              float* __restrict__ ssum) {
    int idx = blockIdx.x * 256 + threadIdx.x;
    if (idx >= NE * NH) return;
    int e = idx >> 3;
    int hh = idx & 7;
    int s = src[e];
    int d = dst[e];
    float x = el[s * NH + hh] + er[d * NH + hh];
    x = (x >= 0.f) ? x : NEG * x;
    atomicAdd(&ssum[d * NH + hh], __expf(x));
}

// ---------------- K4: z[dst,m,:] += fs[src,:] * alpha ----------------
__global__ __launch_bounds__(256) void k_agg(const int* __restrict__ src,
                                             const int* __restrict__ dst,
                                             const float* __restrict__ el,
                                             const float* __restrict__ er,
                                             const float* __restrict__ ssum,
                                             const float* __restrict__ fs,
                                             float* __restrict__ z, int m) {
    int t = threadIdx.x;
    int e = blockIdx.x * 2 + (t >> 7);
    if (e >= NE) return;
    int j = t & 127;
    int hh = j >> 4;
    int s = src[e];
    int d = dst[e];
    float x = el[s * NH + hh] + er[d * NH + hh];
    x = (x >= 0.f) ? x : NEG * x;
    float ex = __expf(x);  // same expression as k_esum -> consistent softmax
    float alpha = ex / fmaxf(ssum[d * NH + hh], 1e-9f);
    atomicAdd(&z[(d * NM + m) * HID + j], fs[s * HID + j] * alpha);
}

// ---------------- K5: elu + semantic attention + output ----------------
__global__ __launch_bounds__(128) void k_sem(const float* __restrict__ z,
                                             const float* __restrict__ Wsem1,
                                             const float* __restrict__ bsem1,
                                             const float* __restrict__ wsem2,
                                             const float* __restrict__ Wout,
                                             const float* __restrict__ bout,
                                             float* __restrict__ out) {
    __shared__ float zel[NM][HID];
    __shared__ float red[HID];
    __shared__ float wm[NM];
    __shared__ float fused[HID];
    int n = blockIdx.x;
    int j = threadIdx.x;
    #pragma unroll
    for (int m = 0; m < NM; m++) {
        float v = z[(n * NM + m) * HID + j];
        zel[m][j] = (v > 0.f) ? v : (__expf(v) - 1.f);  // ELU
    }
    __syncthreads();
    for (int m = 0; m < NM; m++) {
        float acc = bsem1[j];
        #pragma unroll 8
        for (int k = 0; k < HID; k++) acc += zel[m][k] * Wsem1[k * HID + j];
        red[j] = tanhf(acc) * wsem2[j];
        __syncthreads();
        for (int sft = 64; sft > 0; sft >>= 1) {
            if (j < sft) red[j] += red[j + sft];
            __syncthreads();
        }
        if (j == 0) wm[m] = red[0];
        __syncthreads();
    }
    float mx = fmaxf(wm[0], fmaxf(wm[1], wm[2]));
    float e0 = __expf(wm[0] - mx);
    float e1 = __expf(wm[1] - mx);
    float e2 = __expf(wm[2] - mx);
    float inv = 1.f / (e0 + e1 + e2);
    fused[j] = (e0 * zel[0][j] + e1 * zel[1][j] + e2 * zel[2][j]) * inv;
    __syncthreads();
    if (j < NOUT) {
        float acc = bout[j];
        #pragma unroll 8
        for (int k = 0; k < HID; k++) acc += fused[k] * Wout[k * NOUT + j];
        out[n * NOUT + j] = acc;   // fp32 output per reference dtype
    }
}

extern "C" void kernel_launch(void* const* d_in, const int* in_sizes, int n_in,
                              void* d_out, int out_size, void* d_ws, size_t ws_size,
                              hipStream_t stream) {
    (void)in_sizes; (void)n_in; (void)out_size; (void)ws_size;
    const float* feat  = (const float*)d_in[0];
    const float* Wfc   = (const float*)d_in[1];
    const float* bfc   = (const float*)d_in[2];
    const float* Wsrc  = (const float*)d_in[3];
    const float* Wdst  = (const float*)d_in[4];
    const float* al    = (const float*)d_in[5];
    const float* ar    = (const float*)d_in[6];
    const float* Wsem1 = (const float*)d_in[7];
    const float* bsem1 = (const float*)d_in[8];
    const float* wsem2 = (const float*)d_in[9];
    const float* Wout  = (const float*)d_in[10];
    const float* bout  = (const float*)d_in[11];
    const int* srcI    = (const int*)d_in[12];
    const int* dstI    = (const int*)d_in[13];
    float* out = (float*)d_out;

    // workspace layout (fp32): h | z | fs | el | er | ssum  (~132.8 MB)
    float* h    = (float*)d_ws;
    float* z    = h  + (size_t)N_NODES * HID;
    float* fs   = z  + (size_t)N_NODES * NM * HID;
    float* el   = fs + (size_t)N_NODES * HID;
    float* er   = el + (size_t)N_NODES * NH;
    float* ssum = er + (size_t)N_NODES * NH;

    hipMemsetAsync(z, 0, (size_t)N_NODES * NM * HID * sizeof(float), stream);

    k_fc<<<N_NODES, 128, 0, stream>>>(feat, Wfc, bfc, h);

    for (int m = 0; m < NM; m++) {
        k_proj<<<N_NODES, 128, 0, stream>>>(h, Wsrc + (size_t)m * HID * HID,
                                            Wdst + (size_t)m * HID * HID,
                                            al + m * NH * DH, ar + m * NH * DH,
                                            fs, el, er);
        hipMemsetAsync(ssum, 0, (size_t)N_NODES * NH * sizeof(float), stream);
        k_esum<<<(NE * NH + 255) / 256, 256, 0, stream>>>(srcI + (size_t)m * NE,
                                                          dstI + (size_t)m * NE,
                                                          el, er, ssum);
        k_agg<<<NE / 2, 256, 0, stream>>>(srcI + (size_t)m * NE,
                                          dstI + (size_t)m * NE,
                                          el, er, ssum, fs, z, m);
    }

    k_sem<<<N_NODES, 128, 0, stream>>>(z, Wsem1, bsem1, wsem2, Wout, bout, out);
}

// Round 4
// 1432.902 us; speedup vs baseline: 1.6739x; 1.6739x over previous
//
#include <hip/hip_runtime.h>
#include <hip/hip_bf16.h>

#define N_NODES 50000
#define F_IN 256
#define HID 128
#define NH 8
#define DH 16
#define NE 800000
#define NM 3
#define NOUT 8
#define NEG 0.2f

// ---------------- CSR build: histogram / scan / scatter ----------------
__global__ __launch_bounds__(256) void k_hist(const int* __restrict__ dst,
                                              int* __restrict__ deg) {
    int e = blockIdx.x * 256 + threadIdx.x;
    int m = blockIdx.y;
    if (e >= NE) return;
    atomicAdd(&deg[m * N_NODES + dst[(size_t)m * NE + e]], 1);
}

// one block per metapath; exclusive scan of deg -> offs, deg becomes cursor
__global__ __launch_bounds__(256) void k_scan(int* __restrict__ deg,
                                              int* __restrict__ offs) {
    int m = blockIdx.x;
    int* dm = deg + (size_t)m * N_NODES;
    int* om = offs + (size_t)m * (N_NODES + 1);
    __shared__ int part[256];
    __shared__ int basev[256];
    int t = threadIdx.x;
    const int CH = (N_NODES + 255) / 256;  // 196
    int lo = t * CH;
    int hi = lo + CH; if (hi > N_NODES) hi = N_NODES;
    int s = 0;
    for (int i = lo; i < hi; i++) s += dm[i];
    part[t] = s;
    __syncthreads();
    if (t == 0) {
        int run = 0;
        for (int i = 0; i < 256; i++) { basev[i] = run; run += part[i]; }
    }
    __syncthreads();
    int run = basev[t];
    for (int i = lo; i < hi; i++) {
        int c = dm[i];
        om[i] = run;
        dm[i] = run;   // cursor init for scatter
        run += c;
    }
    if (t == 255) om[N_NODES] = run;   // == NE
}

__global__ __launch_bounds__(256) void k_scatter(const int* __restrict__ src,
                                                 const int* __restrict__ dst,
                                                 int* __restrict__ cursor,
                                                 int* __restrict__ ssrc) {
    int e = blockIdx.x * 256 + threadIdx.x;
    int m = blockIdx.y;
    if (e >= NE) return;
    int d = dst[(size_t)m * NE + e];
    int sv = src[(size_t)m * NE + e];
    int pos = atomicAdd(&cursor[m * N_NODES + d], 1);
    ssrc[(size_t)m * NE + pos] = sv;
}

// ---------------- K1: h = features @ W_fc + b_fc (4 nodes/block) ----------------
__global__ __launch_bounds__(128) void k_fc(const float* __restrict__ feat,
                                            const float* __restrict__ Wfc,
                                            const float* __restrict__ bfc,
                                            float* __restrict__ h) {
    __shared__ float rows[4][F_IN];
    int n0 = blockIdx.x * 4;
    int j = threadIdx.x;
    #pragma unroll
    for (int r = 0; r < 4; r++) {
        rows[r][j]       = feat[(size_t)(n0 + r) * F_IN + j];
        rows[r][j + 128] = feat[(size_t)(n0 + r) * F_IN + j + 128];
    }
    __syncthreads();
    float b = bfc[j];
    float acc[4] = {b, b, b, b};
    #pragma unroll 4
    for (int k = 0; k < F_IN; k++) {
        float w = Wfc[k * HID + j];
        #pragma unroll
        for (int r = 0; r < 4; r++) acc[r] += rows[r][k] * w;
    }
    #pragma unroll
    for (int r = 0; r < 4; r++) h[(size_t)(n0 + r) * HID + j] = acc[r];
}

// ---------------- K2: fs = h@Wsrc, el/er (4 nodes/block) ----------------
__global__ __launch_bounds__(128) void k_proj(const float* __restrict__ h,
                                              const float* __restrict__ Wsrc,
                                              const float* __restrict__ Wdst,
                                              const float* __restrict__ al,
                                              const float* __restrict__ ar,
                                              float* __restrict__ fs,
                                              float* __restrict__ el,
                                              float* __restrict__ er) {
    __shared__ float rows[4][HID];
    __shared__ float ps[4][HID];
    __shared__ float pr[4][HID];
    int n0 = blockIdx.x * 4;
    int j = threadIdx.x;
    #pragma unroll
    for (int r = 0; r < 4; r++) rows[r][j] = h[(size_t)(n0 + r) * HID + j];
    __syncthreads();
    float a[4] = {0.f, 0.f, 0.f, 0.f};
    float b[4] = {0.f, 0.f, 0.f, 0.f};
    #pragma unroll 4
    for (int k = 0; k < HID; k++) {
        float ws = Wsrc[k * HID + j];
        float wd = Wdst[k * HID + j];
        #pragma unroll
        for (int r = 0; r < 4; r++) { a[r] += rows[r][k] * ws; b[r] += rows[r][k] * wd; }
    }
    float alj = al[j], arj = ar[j];
    #pragma unroll
    for (int r = 0; r < 4; r++) {
        fs[(size_t)(n0 + r) * HID + j] = a[r];
        ps[r][j] = a[r] * alj;
        pr[r][j] = b[r] * arj;
    }
    __syncthreads();
    if (j < 32) {
        int r = j >> 3, hh = j & 7;
        float sl = 0.f, sr = 0.f;
        #pragma unroll
        for (int d2 = 0; d2 < DH; d2++) {
            sl += ps[r][hh * DH + d2];
            sr += pr[r][hh * DH + d2];
        }
        el[(n0 + r) * NH + hh] = sl;
        er[(n0 + r) * NH + hh] = sr;
    }
}

// ---------------- K3: per-dst-node GAT aggregation, no atomics ----------------
__global__ __launch_bounds__(128) void k_gat(const int* __restrict__ ssrc,
                                             const int* __restrict__ offs,
                                             const float* __restrict__ el,
                                             const float* __restrict__ er,
                                             const float* __restrict__ fs,
                                             float* __restrict__ z, int m) {
    __shared__ float lds_part[128];
    __shared__ float inv_sum[NH];
    int d = blockIdx.x;
    int j = threadIdx.x;
    int s0 = offs[d], s1 = offs[d + 1];
    // pass 1: sum of exp per head (16 slots x 8 heads)
    int t = j >> 3, hh2 = j & 7;
    float erd2 = er[d * NH + hh2];
    float part = 0.f;
    for (int i = s0 + t; i < s1; i += 16) {
        int s = ssrc[i];
        float x = el[s * NH + hh2] + erd2;
        x = (x >= 0.f) ? x : NEG * x;
        part += __expf(x);
    }
    lds_part[j] = part;
    __syncthreads();
    if (j < NH) {
        float acc = 0.f;
        #pragma unroll
        for (int t2 = 0; t2 < 16; t2++) acc += lds_part[t2 * 8 + j];
        inv_sum[j] = 1.f / fmaxf(acc, 1e-9f);
    }
    __syncthreads();
    // pass 2: weighted aggregation
    int hh = j >> 4;
    float erd = er[d * NH + hh];
    float inv = inv_sum[hh];
    float acc = 0.f;
    for (int i = s0; i < s1; i++) {
        int s = ssrc[i];
        float x = el[s * NH + hh] + erd;
        x = (x >= 0.f) ? x : NEG * x;
        float alpha = __expf(x) * inv;
        acc += fs[(size_t)s * HID + j] * alpha;
    }
    z[(size_t)(d * NM + m) * HID + j] = acc;
}

// ---------------- K5: elu + semantic attention + output ----------------
__global__ __launch_bounds__(128) void k_sem(const float* __restrict__ z,
                                             const float* __restrict__ Wsem1,
                                             const float* __restrict__ bsem1,
                                             const float* __restrict__ wsem2,
                                             const float* __restrict__ Wout,
                                             const float* __restrict__ bout,
                                             float* __restrict__ out) {
    __shared__ float zel[NM][HID];
    __shared__ float wred[2];
    __shared__ float wm[NM];
    __shared__ float fused[HID];
    int n = blockIdx.x;
    int j = threadIdx.x;
    #pragma unroll
    for (int m = 0; m < NM; m++) {
        float v = z[(size_t)(n * NM + m) * HID + j];
        zel[m][j] = (v > 0.f) ? v : (__expf(v) - 1.f);  // ELU
    }
    __syncthreads();
    for (int m = 0; m < NM; m++) {
        float acc = bsem1[j];
        #pragma unroll 4
        for (int k = 0; k < HID; k++) acc += zel[m][k] * Wsem1[k * HID + j];
        float v = tanhf(acc) * wsem2[j];
        #pragma unroll
        for (int o = 32; o > 0; o >>= 1) v += __shfl_down(v, o);
        if ((j & 63) == 0) wred[j >> 6] = v;
        __syncthreads();
        if (j == 0) wm[m] = wred[0] + wred[1];
        __syncthreads();
    }
    float mx = fmaxf(wm[0], fmaxf(wm[1], wm[2]));
    float e0 = __expf(wm[0] - mx);
    float e1 = __expf(wm[1] - mx);
    float e2 = __expf(wm[2] - mx);
    float inv = 1.f / (e0 + e1 + e2);
    fused[j] = (e0 * zel[0][j] + e1 * zel[1][j] + e2 * zel[2][j]) * inv;
    __syncthreads();
    if (j < NOUT) {
        float acc = bout[j];
        #pragma unroll 4
        for (int k = 0; k < HID; k++) acc += fused[k] * Wout[k * NOUT + j];
        out[n * NOUT + j] = acc;
    }
}

extern "C" void kernel_launch(void* const* d_in, const int* in_sizes, int n_in,
                              void* d_out, int out_size, void* d_ws, size_t ws_size,
                              hipStream_t stream) {
    (void)in_sizes; (void)n_in; (void)out_size; (void)ws_size;
    const float* feat  = (const float*)d_in[0];
    const float* Wfc   = (const float*)d_in[1];
    const float* bfc   = (const float*)d_in[2];
    const float* Wsrc  = (const float*)d_in[3];
    const float* Wdst  = (const float*)d_in[4];
    const float* al    = (const float*)d_in[5];
    const float* ar    = (const float*)d_in[6];
    const float* Wsem1 = (const float*)d_in[7];
    const float* bsem1 = (const float*)d_in[8];
    const float* wsem2 = (const float*)d_in[9];
    const float* Wout  = (const float*)d_in[10];
    const float* bout  = (const float*)d_in[11];
    const int* srcI    = (const int*)d_in[12];
    const int* dstI    = (const int*)d_in[13];
    float* out = (float*)d_out;

    // workspace layout: fp32 h | z | fs | el | er, then int deg | offs | ssrc (~142 MB)
    float* h    = (float*)d_ws;
    float* z    = h  + (size_t)N_NODES * HID;
    float* fs   = z  + (size_t)N_NODES * NM * HID;
    float* el   = fs + (size_t)N_NODES * HID;
    float* er   = el + (size_t)N_NODES * NH;
    int*   deg  = (int*)(er + (size_t)N_NODES * NH);
    int*   offs = deg  + (size_t)NM * N_NODES;
    int*   ssrc = offs + (size_t)NM * (N_NODES + 1);

    // CSR build for all 3 metapaths
    hipMemsetAsync(deg, 0, (size_t)NM * N_NODES * sizeof(int), stream);
    {
        dim3 g((NE + 255) / 256, NM);
        k_hist<<<g, 256, 0, stream>>>(dstI, deg);
        k_scan<<<NM, 256, 0, stream>>>(deg, offs);
        k_scatter<<<g, 256, 0, stream>>>(srcI, dstI, deg, ssrc);
    }

    k_fc<<<N_NODES / 4, 128, 0, stream>>>(feat, Wfc, bfc, h);

    for (int m = 0; m < NM; m++) {
        k_proj<<<N_NODES / 4, 128, 0, stream>>>(h, Wsrc + (size_t)m * HID * HID,
                                                Wdst + (size_t)m * HID * HID,
                                                al + m * NH * DH, ar + m * NH * DH,
                                                fs, el, er);
        k_gat<<<N_NODES, 128, 0, stream>>>(ssrc + (size_t)m * NE,
                                           offs + (size_t)m * (N_NODES + 1),
                                           el, er, fs, z, m);
    }

    k_sem<<<N_NODES, 128, 0, stream>>>(z, Wsem1, bsem1, wsem2, Wout, bout, out);
}